// Round 1
// baseline (652.010 us; speedup 1.0000x reference)
//
#include <hip/hip_runtime.h>

typedef __bf16 bf16;
typedef __attribute__((ext_vector_type(8))) __bf16 bf16x8;
typedef __attribute__((ext_vector_type(4))) float f32x4;

#define S_LEN 2048
#define D_MODEL 2048
#define NHEADS 32
#define NKVH 8
#define HDIM 64
#define BATCH 2

// ---------------- elementwise fp32 -> bf16 ----------------
__global__ void cvt_f32_bf16(const float* __restrict__ in, bf16* __restrict__ out, int n4) {
    int i = blockIdx.x * blockDim.x + threadIdx.x;
    if (i < n4) {
        float4 f = ((const float4*)in)[i];
        union { bf16 h[4]; uint2 u; } t;
        t.h[0] = (bf16)f.x; t.h[1] = (bf16)f.y; t.h[2] = (bf16)f.z; t.h[3] = (bf16)f.w;
        ((uint2*)out)[i] = t.u;
    }
}

// ---------------- W [K][N] fp32 -> Wt [N][K] bf16 ----------------
__global__ void transpose_w(const float* __restrict__ W, bf16* __restrict__ Wt, int K, int N) {
    __shared__ float tile[32][33];
    int kt = blockIdx.y * 32, nt = blockIdx.x * 32;
    int tx = threadIdx.x, ty = threadIdx.y;
    #pragma unroll
    for (int i = 0; i < 32; i += 8)
        tile[ty + i][tx] = W[(size_t)(kt + ty + i) * N + nt + tx];
    __syncthreads();
    #pragma unroll
    for (int i = 0; i < 32; i += 8)
        Wt[(size_t)(nt + ty + i) * K + kt + tx] = (bf16)tile[tx][ty + i];
}

// ---------------- GEMM: C[M][N] = A[M][K] * Bt[N][K]^T, bf16 in, fp32 acc ----------------
// block = 256 threads (4 waves), tile 128x128, K-step 32.
template <bool OUT_BF16>
__global__ __launch_bounds__(256) void gemm_bt(const bf16* __restrict__ A,
                                               const bf16* __restrict__ Bt,
                                               void* __restrict__ Cv,
                                               int M, int N, int K) {
    __shared__ bf16 As[128 * 40];   // stride 40 (pad +8): 2-way bank alias only
    __shared__ bf16 Bs[128 * 40];

    const int tid  = threadIdx.x;
    const int wave = tid >> 6;
    const int lane = tid & 63;
    const int l16  = lane & 15;
    const int quad = lane >> 4;
    const int wrow = (wave >> 1) * 64;
    const int wcol = (wave & 1) * 64;
    const int m0 = blockIdx.y * 128;
    const int n0 = blockIdx.x * 128;

    f32x4 acc[4][4];
    #pragma unroll
    for (int mi = 0; mi < 4; ++mi)
        #pragma unroll
        for (int ni = 0; ni < 4; ++ni)
            acc[mi][ni] = (f32x4){0.f, 0.f, 0.f, 0.f};

    for (int k0 = 0; k0 < K; k0 += 32) {
        __syncthreads();
        #pragma unroll
        for (int i = 0; i < 2; ++i) {
            int idx = i * 256 + tid;
            int r = idx >> 2, oct = idx & 3;
            *(uint4*)&As[r * 40 + oct * 8] = *(const uint4*)(A  + (size_t)(m0 + r) * K + k0 + oct * 8);
            *(uint4*)&Bs[r * 40 + oct * 8] = *(const uint4*)(Bt + (size_t)(n0 + r) * K + k0 + oct * 8);
        }
        __syncthreads();

        bf16x8 af[4], bfr[4];
        #pragma unroll
        for (int mi = 0; mi < 4; ++mi)
            af[mi] = *(const bf16x8*)&As[(wrow + mi * 16 + l16) * 40 + quad * 8];
        #pragma unroll
        for (int ni = 0; ni < 4; ++ni)
            bfr[ni] = *(const bf16x8*)&Bs[(wcol + ni * 16 + l16) * 40 + quad * 8];
        #pragma unroll
        for (int mi = 0; mi < 4; ++mi)
            #pragma unroll
            for (int ni = 0; ni < 4; ++ni)
                acc[mi][ni] = __builtin_amdgcn_mfma_f32_16x16x32_bf16(af[mi], bfr[ni], acc[mi][ni], 0, 0, 0);
    }

    // epilogue: C row = quad*4+reg (+16*mi), col = l16 (+16*ni)
    #pragma unroll
    for (int mi = 0; mi < 4; ++mi) {
        #pragma unroll
        for (int ni = 0; ni < 4; ++ni) {
            #pragma unroll
            for (int r = 0; r < 4; ++r) {
                size_t row = (size_t)(m0 + wrow + mi * 16 + quad * 4 + r);
                size_t col = (size_t)(n0 + wcol + ni * 16 + l16);
                if (OUT_BF16) ((bf16*)Cv)[row * N + col] = (bf16)acc[mi][ni][r];
                else          ((float*)Cv)[row * N + col] = acc[mi][ni][r];
            }
        }
    }
}

// ---------------- RoPE + relayout ----------------
// Qf [b][s][h*64+d] -> Qr [b][h][s][64] (roped);  Kf likewise; Vf relayout only.
__global__ void rope_relayout(const bf16* __restrict__ Qf, const bf16* __restrict__ Kf,
                              const bf16* __restrict__ Vf, bf16* __restrict__ Qr,
                              bf16* __restrict__ Kr, bf16* __restrict__ Vr) {
    const int QN = BATCH * S_LEN * NHEADS * 32;  // 4194304
    const int KN = BATCH * S_LEN * NKVH * 32;    // 1048576
    int idx = blockIdx.x * 256 + threadIdx.x;
    if (idx < QN) {
        int j = idx & 31, hh = (idx >> 5) & 31, s = (idx >> 10) & 2047, bb = idx >> 21;
        size_t src = ((size_t)(bb * S_LEN + s)) * D_MODEL + hh * HDIM + j;
        float x1 = (float)Qf[src], x2 = (float)Qf[src + 32];
        float ang = (float)s * powf(10000.0f, -(float)j * (1.0f / 32.0f));
        float sn, cs; sincosf(ang, &sn, &cs);
        size_t dst = ((size_t)((bb * NHEADS + hh) * S_LEN + s)) * HDIM + j;
        Qr[dst]      = (bf16)(x1 * cs - x2 * sn);
        Qr[dst + 32] = (bf16)(x2 * cs + x1 * sn);
    } else if (idx < QN + KN) {
        int t = idx - QN;
        int j = t & 31, hh = (t >> 5) & 7, s = (t >> 8) & 2047, bb = t >> 19;
        size_t src = ((size_t)(bb * S_LEN + s)) * 512 + hh * HDIM + j;
        float x1 = (float)Kf[src], x2 = (float)Kf[src + 32];
        float ang = (float)s * powf(10000.0f, -(float)j * (1.0f / 32.0f));
        float sn, cs; sincosf(ang, &sn, &cs);
        size_t dst = ((size_t)((bb * NKVH + hh) * S_LEN + s)) * HDIM + j;
        Kr[dst]      = (bf16)(x1 * cs - x2 * sn);
        Kr[dst + 32] = (bf16)(x2 * cs + x1 * sn);
    } else if (idx < QN + 2 * KN) {
        int t = idx - QN - KN;
        int j = t & 31, hh = (t >> 5) & 7, s = (t >> 8) & 2047, bb = t >> 19;
        size_t src = ((size_t)(bb * S_LEN + s)) * 512 + hh * HDIM + j;
        size_t dst = ((size_t)((bb * NKVH + hh) * S_LEN + s)) * HDIM + j;
        Vr[dst]      = Vf[src];
        Vr[dst + 32] = Vf[src + 32];
    }
}

// ---------------- Flash attention (causal GQA) ----------------
// grid = B*NH*(S/64); block = 256 (4 waves); each wave owns 16 q-rows; 32-key KV tiles.
__global__ __launch_bounds__(256) void attn_kernel(const bf16* __restrict__ Q,
                                                   const bf16* __restrict__ K,
                                                   const bf16* __restrict__ V,
                                                   bf16* __restrict__ Ctx) {
    __shared__ bf16 Ks[32 * 72];    // [key][dim], stride 72
    __shared__ bf16 Vst[64 * 40];   // [dim][key], stride 40 (transposed for PV B-frag)
    __shared__ bf16 Ps[4 * 16 * 40];// per-wave P relayout buffer

    const int bx = blockIdx.x;
    const int qt = bx & 31;
    const int h  = (bx >> 5) & 31;
    const int b  = bx >> 10;
    const int kvh = h >> 2;
    const int tid = threadIdx.x;
    const int wave = tid >> 6;
    const int lane = tid & 63;
    const int l16  = lane & 15;
    const int quad = lane >> 4;

    const bf16* Qb = Q + ((size_t)(b * NHEADS + h) * S_LEN) * HDIM;
    const bf16* Kb = K + ((size_t)(b * NKVH + kvh) * S_LEN) * HDIM;
    const bf16* Vb = V + ((size_t)(b * NKVH + kvh) * S_LEN) * HDIM;

    const int q0 = qt * 64;
    const int qrow = wave * 16 + l16;

    bf16x8 aq0 = *(const bf16x8*)(Qb + (size_t)(q0 + qrow) * HDIM + quad * 8);
    bf16x8 aq1 = *(const bf16x8*)(Qb + (size_t)(q0 + qrow) * HDIM + 32 + quad * 8);

    f32x4 o0 = {0.f,0.f,0.f,0.f}, o1 = o0, o2 = o0, o3 = o0;
    float m_i[4], l_i[4];
    #pragma unroll
    for (int r = 0; r < 4; ++r) { m_i[r] = -1e30f; l_i[r] = 0.f; }

    const int ktiles = 2 * (qt + 1);
    for (int kt = 0; kt < ktiles; ++kt) {
        const int k0 = kt * 32;
        __syncthreads();
        {   // stage K (row-major) and V (transposed)
            int row = tid >> 3, oct = tid & 7;
            *(uint4*)&Ks[row * 72 + oct * 8] = *(const uint4*)(Kb + (size_t)(k0 + row) * HDIM + oct * 8);
            int d = tid & 63, kg = tid >> 6;
            union { bf16 hh[8]; uint4 u; } tmp;
            #pragma unroll
            for (int i = 0; i < 8; ++i) tmp.hh[i] = Vb[(size_t)(k0 + kg * 8 + i) * HDIM + d];
            *(uint4*)&Vst[d * 40 + kg * 8] = tmp.u;
        }
        __syncthreads();

        // S = Q K^T for 32 keys (2 column tiles x 2 K-steps)
        f32x4 sc0 = {0.f,0.f,0.f,0.f}, sc1 = sc0;
        {
            bf16x8 b00 = *(const bf16x8*)&Ks[l16 * 72 + quad * 8];
            bf16x8 b01 = *(const bf16x8*)&Ks[l16 * 72 + 32 + quad * 8];
            bf16x8 b10 = *(const bf16x8*)&Ks[(16 + l16) * 72 + quad * 8];
            bf16x8 b11 = *(const bf16x8*)&Ks[(16 + l16) * 72 + 32 + quad * 8];
            sc0 = __builtin_amdgcn_mfma_f32_16x16x32_bf16(aq0, b00, sc0, 0, 0, 0);
            sc0 = __builtin_amdgcn_mfma_f32_16x16x32_bf16(aq1, b01, sc0, 0, 0, 0);
            sc1 = __builtin_amdgcn_mfma_f32_16x16x32_bf16(aq0, b10, sc1, 0, 0, 0);
            sc1 = __builtin_amdgcn_mfma_f32_16x16x32_bf16(aq1, b11, sc1, 0, 0, 0);
        }
        const int qbase = q0 + wave * 16 + quad * 4;
        if (kt >= 2 * qt) {  // diagonal tiles: causal mask
            #pragma unroll
            for (int r = 0; r < 4; ++r) {
                int qi = qbase + r;
                sc0[r] = (k0 + l16      <= qi) ? sc0[r] * 0.125f : -1e30f;
                sc1[r] = (k0 + 16 + l16 <= qi) ? sc1[r] * 0.125f : -1e30f;
            }
        } else {
            #pragma unroll
            for (int r = 0; r < 4; ++r) { sc0[r] *= 0.125f; sc1[r] *= 0.125f; }
        }
        // online softmax (rows live on 16-lane groups)
        float mx[4];
        #pragma unroll
        for (int r = 0; r < 4; ++r) mx[r] = fmaxf(sc0[r], sc1[r]);
        #pragma unroll
        for (int off = 1; off < 16; off <<= 1) {
            #pragma unroll
            for (int r = 0; r < 4; ++r) mx[r] = fmaxf(mx[r], __shfl_xor(mx[r], off));
        }
        float al[4];
        #pragma unroll
        for (int r = 0; r < 4; ++r) {
            float mn = fmaxf(m_i[r], mx[r]);
            al[r] = __expf(m_i[r] - mn);
            m_i[r] = mn;
        }
        float rs[4];
        #pragma unroll
        for (int r = 0; r < 4; ++r) {
            float p0 = __expf(sc0[r] - m_i[r]);
            float p1 = __expf(sc1[r] - m_i[r]);
            sc0[r] = p0; sc1[r] = p1;
            rs[r] = p0 + p1;
        }
        #pragma unroll
        for (int off = 1; off < 16; off <<= 1) {
            #pragma unroll
            for (int r = 0; r < 4; ++r) rs[r] += __shfl_xor(rs[r], off);
        }
        #pragma unroll
        for (int r = 0; r < 4; ++r) l_i[r] = l_i[r] * al[r] + rs[r];
        #pragma unroll
        for (int r = 0; r < 4; ++r) { o0[r] *= al[r]; o1[r] *= al[r]; o2[r] *= al[r]; o3[r] *= al[r]; }

        // P (C-layout) -> LDS -> A-layout (per-wave region, in-wave LDS ordering)
        bf16* pw = &Ps[wave * 16 * 40];
        #pragma unroll
        for (int r = 0; r < 4; ++r) {
            pw[(quad * 4 + r) * 40 + l16]      = (bf16)sc0[r];
            pw[(quad * 4 + r) * 40 + 16 + l16] = (bf16)sc1[r];
        }
        bf16x8 ap  = *(const bf16x8*)&pw[l16 * 40 + quad * 8];
        bf16x8 bv0 = *(const bf16x8*)&Vst[l16 * 40 + quad * 8];
        bf16x8 bv1 = *(const bf16x8*)&Vst[(16 + l16) * 40 + quad * 8];
        bf16x8 bv2 = *(const bf16x8*)&Vst[(32 + l16) * 40 + quad * 8];
        bf16x8 bv3 = *(const bf16x8*)&Vst[(48 + l16) * 40 + quad * 8];
        o0 = __builtin_amdgcn_mfma_f32_16x16x32_bf16(ap, bv0, o0, 0, 0, 0);
        o1 = __builtin_amdgcn_mfma_f32_16x16x32_bf16(ap, bv1, o1, 0, 0, 0);
        o2 = __builtin_amdgcn_mfma_f32_16x16x32_bf16(ap, bv2, o2, 0, 0, 0);
        o3 = __builtin_amdgcn_mfma_f32_16x16x32_bf16(ap, bv3, o3, 0, 0, 0);
    }

    // epilogue: Ctx[b][s][h*64 + d] bf16
    #pragma unroll
    for (int r = 0; r < 4; ++r) {
        float inv = 1.0f / l_i[r];
        size_t row = (size_t)b * S_LEN + q0 + wave * 16 + quad * 4 + r;
        bf16* dst = Ctx + row * D_MODEL + h * HDIM;
        dst[l16]      = (bf16)(o0[r] * inv);
        dst[16 + l16] = (bf16)(o1[r] * inv);
        dst[32 + l16] = (bf16)(o2[r] * inv);
        dst[48 + l16] = (bf16)(o3[r] * inv);
    }
}

extern "C" void kernel_launch(void* const* d_in, const int* in_sizes, int n_in,
                              void* d_out, int out_size, void* d_ws, size_t ws_size,
                              hipStream_t stream) {
    const float* x  = (const float*)d_in[0];
    const float* Wq = (const float*)d_in[1];
    const float* Wk = (const float*)d_in[2];
    const float* Wv = (const float*)d_in[3];
    const float* Wo = (const float*)d_in[4];

    char* p = (char*)d_ws;
    bf16* X16 = (bf16*)p; p += (size_t)4096 * 2048 * 2;
    bf16* WqT = (bf16*)p; p += (size_t)2048 * 2048 * 2;
    bf16* WkT = (bf16*)p; p += (size_t)512 * 2048 * 2;
    bf16* WvT = (bf16*)p; p += (size_t)512 * 2048 * 2;
    bf16* WoT = (bf16*)p; p += (size_t)2048 * 2048 * 2;
    bf16* Qf  = (bf16*)p; p += (size_t)4096 * 2048 * 2;
    bf16* Kf  = (bf16*)p; p += (size_t)4096 * 512 * 2;
    bf16* Vf  = (bf16*)p; p += (size_t)4096 * 512 * 2;
    bf16* Qr  = (bf16*)p; p += (size_t)4096 * 2048 * 2;
    bf16* Kr  = (bf16*)p; p += (size_t)4096 * 512 * 2;
    bf16* Vr  = (bf16*)p; p += (size_t)4096 * 512 * 2;
    bf16* Ctx = Qf;  // Qf is dead after rope_relayout; reuse for attention output

    cvt_f32_bf16<<<8192, 256, 0, stream>>>(x, X16, 2097152);
    transpose_w<<<dim3(64, 64), dim3(32, 8), 0, stream>>>(Wq, WqT, 2048, 2048);
    transpose_w<<<dim3(16, 64), dim3(32, 8), 0, stream>>>(Wk, WkT, 2048, 512);
    transpose_w<<<dim3(16, 64), dim3(32, 8), 0, stream>>>(Wv, WvT, 2048, 512);
    transpose_w<<<dim3(64, 64), dim3(32, 8), 0, stream>>>(Wo, WoT, 2048, 2048);

    gemm_bt<true><<<dim3(16, 32), 256, 0, stream>>>(X16, WqT, (void*)Qf, 4096, 2048, 2048);
    gemm_bt<true><<<dim3(4, 32),  256, 0, stream>>>(X16, WkT, (void*)Kf, 4096, 512, 2048);
    gemm_bt<true><<<dim3(4, 32),  256, 0, stream>>>(X16, WvT, (void*)Vf, 4096, 512, 2048);

    rope_relayout<<<24576, 256, 0, stream>>>(Qf, Kf, Vf, Qr, Kr, Vr);
    attn_kernel<<<2048, 256, 0, stream>>>(Qr, Kr, Vr, Ctx);

    gemm_bt<false><<<dim3(16, 32), 256, 0, stream>>>(Ctx, WoT, d_out, 4096, 2048, 2048);
}

// Round 2
// 457.704 us; speedup vs baseline: 1.4245x; 1.4245x over previous
//
#include <hip/hip_runtime.h>

typedef __bf16 bf16;
typedef __attribute__((ext_vector_type(8))) __bf16 bf16x8;
typedef __attribute__((ext_vector_type(4))) float f32x4;

#define S_LEN 2048
#define D_MODEL 2048
#define NHEADS 32
#define NKVH 8
#define HDIM 64
#define BATCH 2

// ---------------- elementwise fp32 -> bf16 ----------------
__global__ void cvt_f32_bf16(const float* __restrict__ in, bf16* __restrict__ out, int n4) {
    int i = blockIdx.x * blockDim.x + threadIdx.x;
    if (i < n4) {
        float4 f = ((const float4*)in)[i];
        union { bf16 h[4]; uint2 u; } t;
        t.h[0] = (bf16)f.x; t.h[1] = (bf16)f.y; t.h[2] = (bf16)f.z; t.h[3] = (bf16)f.w;
        ((uint2*)out)[i] = t.u;
    }
}

// ---------------- W [K][N] fp32 -> Wt [N][K] bf16 ----------------
__global__ void transpose_w(const float* __restrict__ W, bf16* __restrict__ Wt, int K, int N) {
    __shared__ float tile[32][33];
    int kt = blockIdx.y * 32, nt = blockIdx.x * 32;
    int tx = threadIdx.x, ty = threadIdx.y;
    #pragma unroll
    for (int i = 0; i < 32; i += 8)
        tile[ty + i][tx] = W[(size_t)(kt + ty + i) * N + nt + tx];
    __syncthreads();
    #pragma unroll
    for (int i = 0; i < 32; i += 8)
        Wt[(size_t)(nt + ty + i) * K + kt + tx] = (bf16)tile[tx][ty + i];
}

// ---------------- V [b][s][kvh*64+d] bf16 -> Vt [b*8+kvh][d][s] bf16 ----------------
__global__ void transpose_v(const bf16* __restrict__ Vf, bf16* __restrict__ Vt) {
    __shared__ bf16 tl[32][33];
    int z = blockIdx.z;               // b*8+kvh
    int s0 = blockIdx.x * 32, d0 = blockIdx.y * 32;
    int bb = z >> 3, hh = z & 7;
    int tx = threadIdx.x, ty = threadIdx.y;
    #pragma unroll
    for (int i = 0; i < 32; i += 8)
        tl[ty + i][tx] = Vf[((size_t)(bb * S_LEN + s0 + ty + i)) * 512 + hh * 64 + d0 + tx];
    __syncthreads();
    #pragma unroll
    for (int i = 0; i < 32; i += 8)
        Vt[((size_t)z * 64 + d0 + ty + i) * S_LEN + s0 + tx] = tl[tx][ty + i];
}

// ---------------- GEMM: C[M][N] = A[M][K] * Bt[N][K]^T, bf16 in, fp32 acc ----------------
template <bool OUT_BF16>
__global__ __launch_bounds__(256) void gemm_bt(const bf16* __restrict__ A,
                                               const bf16* __restrict__ Bt,
                                               void* __restrict__ Cv,
                                               int M, int N, int K) {
    __shared__ bf16 As[128 * 40];
    __shared__ bf16 Bs[128 * 40];

    const int tid  = threadIdx.x;
    const int wave = tid >> 6;
    const int lane = tid & 63;
    const int l16  = lane & 15;
    const int quad = lane >> 4;
    const int wrow = (wave >> 1) * 64;
    const int wcol = (wave & 1) * 64;
    const int m0 = blockIdx.y * 128;
    const int n0 = blockIdx.x * 128;

    f32x4 acc[4][4];
    #pragma unroll
    for (int mi = 0; mi < 4; ++mi)
        #pragma unroll
        for (int ni = 0; ni < 4; ++ni)
            acc[mi][ni] = (f32x4){0.f, 0.f, 0.f, 0.f};

    for (int k0 = 0; k0 < K; k0 += 32) {
        __syncthreads();
        #pragma unroll
        for (int i = 0; i < 2; ++i) {
            int idx = i * 256 + tid;
            int r = idx >> 2, oct = idx & 3;
            *(uint4*)&As[r * 40 + oct * 8] = *(const uint4*)(A  + (size_t)(m0 + r) * K + k0 + oct * 8);
            *(uint4*)&Bs[r * 40 + oct * 8] = *(const uint4*)(Bt + (size_t)(n0 + r) * K + k0 + oct * 8);
        }
        __syncthreads();

        bf16x8 af[4], bfr[4];
        #pragma unroll
        for (int mi = 0; mi < 4; ++mi)
            af[mi] = *(const bf16x8*)&As[(wrow + mi * 16 + l16) * 40 + quad * 8];
        #pragma unroll
        for (int ni = 0; ni < 4; ++ni)
            bfr[ni] = *(const bf16x8*)&Bs[(wcol + ni * 16 + l16) * 40 + quad * 8];
        #pragma unroll
        for (int mi = 0; mi < 4; ++mi)
            #pragma unroll
            for (int ni = 0; ni < 4; ++ni)
                acc[mi][ni] = __builtin_amdgcn_mfma_f32_16x16x32_bf16(af[mi], bfr[ni], acc[mi][ni], 0, 0, 0);
    }

    #pragma unroll
    for (int mi = 0; mi < 4; ++mi) {
        #pragma unroll
        for (int ni = 0; ni < 4; ++ni) {
            #pragma unroll
            for (int r = 0; r < 4; ++r) {
                size_t row = (size_t)(m0 + wrow + mi * 16 + quad * 4 + r);
                size_t col = (size_t)(n0 + wcol + ni * 16 + l16);
                if (OUT_BF16) ((bf16*)Cv)[row * N + col] = (bf16)acc[mi][ni][r];
                else          ((float*)Cv)[row * N + col] = acc[mi][ni][r];
            }
        }
    }
}

// ---------------- RoPE + relayout (Q scaled by 1/8; V handled by transpose_v) ----------------
__global__ void rope_relayout(const bf16* __restrict__ Qf, const bf16* __restrict__ Kf,
                              bf16* __restrict__ Qr, bf16* __restrict__ Kr) {
    const int QN = BATCH * S_LEN * NHEADS * 32;  // 4194304
    const int KN = BATCH * S_LEN * NKVH * 32;    // 1048576
    const float LC = 0.28782313662425572f;       // ln(10000)/32
    int idx = blockIdx.x * 256 + threadIdx.x;
    if (idx < QN) {
        int j = idx & 31, hh = (idx >> 5) & 31, s = (idx >> 10) & 2047, bb = idx >> 21;
        size_t src = ((size_t)(bb * S_LEN + s)) * D_MODEL + hh * HDIM + j;
        float x1 = (float)Qf[src], x2 = (float)Qf[src + 32];
        float ang = (float)s * __expf(-(float)j * LC);
        float sn, cs; sincosf(ang, &sn, &cs);
        size_t dst = ((size_t)((bb * NHEADS + hh) * S_LEN + s)) * HDIM + j;
        Qr[dst]      = (bf16)((x1 * cs - x2 * sn) * 0.125f);
        Qr[dst + 32] = (bf16)((x2 * cs + x1 * sn) * 0.125f);
    } else if (idx < QN + KN) {
        int t = idx - QN;
        int j = t & 31, hh = (t >> 5) & 7, s = (t >> 8) & 2047, bb = t >> 19;
        size_t src = ((size_t)(bb * S_LEN + s)) * 512 + hh * HDIM + j;
        float x1 = (float)Kf[src], x2 = (float)Kf[src + 32];
        float ang = (float)s * __expf(-(float)j * LC);
        float sn, cs; sincosf(ang, &sn, &cs);
        size_t dst = ((size_t)((bb * NKVH + hh) * S_LEN + s)) * HDIM + j;
        Kr[dst]      = (bf16)(x1 * cs - x2 * sn);
        Kr[dst + 32] = (bf16)(x2 * cs + x1 * sn);
    }
}

// ---------------- Flash attention (causal GQA) ----------------
// grid = B*NH*8 pair-blocks; block = 256 (4 waves). Each block processes q-tiles
// {p, 15-p} (128 rows each) sequentially -> uniform 17 KV-iters of 128 keys.
// Wave owns 32 q-rows (2 x 16-row MFMA fragments).
__global__ __launch_bounds__(256, 2) void attn_kernel(const bf16* __restrict__ Q,
                                                      const bf16* __restrict__ K,
                                                      const bf16* __restrict__ Vt,
                                                      bf16* __restrict__ Ctx) {
    __shared__ bf16 KsL[128 * 72];    // [key][dim] stride 72 (36 dw: balanced banks)
    __shared__ bf16 VtL[64 * 138];    // [dim][key] stride 138 (69 dw: odd-mod-4)
    __shared__ bf16 Ps[4 * 32 * 40];  // per-wave P chunk [32 q][32 k + pad]

    const int bx = blockIdx.x;
    const int pp = bx & 7;
    const int h  = (bx >> 3) & 31;
    const int b  = bx >> 8;
    const int kvh = h >> 2;
    const int tid = threadIdx.x;
    const int wave = tid >> 6;
    const int lane = tid & 63;
    const int l16  = lane & 15;
    const int quad = lane >> 4;

    const bf16* Qb = Q  + ((size_t)(b * NHEADS + h)) * S_LEN * HDIM;
    const bf16* Kb = K  + ((size_t)(b * NKVH + kvh)) * S_LEN * HDIM;
    const bf16* Vb = Vt + ((size_t)(b * NKVH + kvh)) * HDIM * S_LEN;
    bf16* Psw = &Ps[wave * 32 * 40];

    #pragma unroll 1
    for (int t = 0; t < 2; ++t) {
        const int qt = (t == 0) ? pp : 15 - pp;
        const int q0 = qt * 128;

        bf16x8 aq[2][2];
        #pragma unroll
        for (int qf = 0; qf < 2; ++qf)
            #pragma unroll
            for (int ks = 0; ks < 2; ++ks)
                aq[qf][ks] = *(const bf16x8*)(Qb + (size_t)(q0 + wave * 32 + qf * 16 + l16) * HDIM + ks * 32 + quad * 8);

        f32x4 O[2][4];
        float m_i[2][4], l_i[2][4];
        #pragma unroll
        for (int qf = 0; qf < 2; ++qf)
            #pragma unroll
            for (int r = 0; r < 4; ++r) {
                m_i[qf][r] = -1e30f; l_i[qf][r] = 0.f;
                O[qf][r] = (f32x4){0.f,0.f,0.f,0.f};  // note: O[qf][df], init all df below
            }
        #pragma unroll
        for (int qf = 0; qf < 2; ++qf)
            #pragma unroll
            for (int df = 0; df < 4; ++df)
                O[qf][df] = (f32x4){0.f,0.f,0.f,0.f};

        #pragma unroll 1
        for (int kt = 0; kt <= qt; ++kt) {
            const int k0 = kt * 128;
            __syncthreads();
            #pragma unroll
            for (int i = 0; i < 4; ++i) {
                int c = i * 256 + tid;
                int kr = c >> 3, cc = c & 7;
                *(uint4*)&KsL[kr * 72 + cc * 8] = *(const uint4*)(Kb + (size_t)(k0 + kr) * HDIM + cc * 8);
                int dr = c >> 4, kc = c & 15;
                *(uint4*)&VtL[dr * 138 + kc * 8] = *(const uint4*)(Vb + (size_t)dr * S_LEN + k0 + kc * 8);
            }
            __syncthreads();

            // ---- S = Q K^T (32q x 128k per wave) ----
            f32x4 sc[2][8];
            #pragma unroll
            for (int qf = 0; qf < 2; ++qf)
                #pragma unroll
                for (int kf = 0; kf < 8; ++kf)
                    sc[qf][kf] = (f32x4){0.f,0.f,0.f,0.f};
            #pragma unroll
            for (int kf = 0; kf < 8; ++kf) {
                #pragma unroll
                for (int ks = 0; ks < 2; ++ks) {
                    bf16x8 bk = *(const bf16x8*)&KsL[(kf * 16 + l16) * 72 + ks * 32 + quad * 8];
                    sc[0][kf] = __builtin_amdgcn_mfma_f32_16x16x32_bf16(aq[0][ks], bk, sc[0][kf], 0, 0, 0);
                    sc[1][kf] = __builtin_amdgcn_mfma_f32_16x16x32_bf16(aq[1][ks], bk, sc[1][kf], 0, 0, 0);
                }
            }

            if (kt == qt) {  // diagonal: causal mask (Q pre-scaled, no mul here)
                #pragma unroll
                for (int qf = 0; qf < 2; ++qf)
                    #pragma unroll
                    for (int kf = 0; kf < 8; ++kf)
                        #pragma unroll
                        for (int r = 0; r < 4; ++r) {
                            int key = kf * 16 + l16;
                            int qi  = wave * 32 + qf * 16 + quad * 4 + r;
                            if (key > qi) sc[qf][kf][r] = -1e30f;
                        }
            }

            // ---- online softmax ----
            float mx[2][4];
            #pragma unroll
            for (int qf = 0; qf < 2; ++qf)
                #pragma unroll
                for (int r = 0; r < 4; ++r) {
                    float v = sc[qf][0][r];
                    #pragma unroll
                    for (int kf = 1; kf < 8; ++kf) v = fmaxf(v, sc[qf][kf][r]);
                    mx[qf][r] = v;
                }
            #pragma unroll
            for (int off = 1; off < 16; off <<= 1)
                #pragma unroll
                for (int qf = 0; qf < 2; ++qf)
                    #pragma unroll
                    for (int r = 0; r < 4; ++r)
                        mx[qf][r] = fmaxf(mx[qf][r], __shfl_xor(mx[qf][r], off));

            #pragma unroll
            for (int qf = 0; qf < 2; ++qf)
                #pragma unroll
                for (int r = 0; r < 4; ++r) {
                    float mn = fmaxf(m_i[qf][r], mx[qf][r]);
                    float alpha = __expf(m_i[qf][r] - mn);
                    m_i[qf][r] = mn;
                    l_i[qf][r] *= alpha;
                    #pragma unroll
                    for (int df = 0; df < 4; ++df) O[qf][df][r] *= alpha;
                }

            float rs[2][4];
            #pragma unroll
            for (int qf = 0; qf < 2; ++qf)
                #pragma unroll
                for (int r = 0; r < 4; ++r) {
                    float s = 0.f;
                    #pragma unroll
                    for (int kf = 0; kf < 8; ++kf) {
                        float pe = __expf(sc[qf][kf][r] - m_i[qf][r]);
                        sc[qf][kf][r] = pe;
                        s += pe;
                    }
                    rs[qf][r] = s;
                }
            #pragma unroll
            for (int off = 1; off < 16; off <<= 1)
                #pragma unroll
                for (int qf = 0; qf < 2; ++qf)
                    #pragma unroll
                    for (int r = 0; r < 4; ++r)
                        rs[qf][r] += __shfl_xor(rs[qf][r], off);
            #pragma unroll
            for (int qf = 0; qf < 2; ++qf)
                #pragma unroll
                for (int r = 0; r < 4; ++r)
                    l_i[qf][r] += rs[qf][r];

            // ---- O += P V : 4 k-steps of 32 keys, P via per-wave LDS relayout ----
            #pragma unroll
            for (int s = 0; s < 4; ++s) {
                #pragma unroll
                for (int qf = 0; qf < 2; ++qf)
                    #pragma unroll
                    for (int f = 0; f < 2; ++f)
                        #pragma unroll
                        for (int r = 0; r < 4; ++r)
                            Psw[(qf * 16 + quad * 4 + r) * 40 + f * 16 + l16] = (bf16)sc[qf][2 * s + f][r];
                bf16x8 ap0 = *(const bf16x8*)&Psw[l16 * 40 + quad * 8];
                bf16x8 ap1 = *(const bf16x8*)&Psw[(16 + l16) * 40 + quad * 8];
                #pragma unroll
                for (int df = 0; df < 4; ++df) {
                    bf16x8 bv = *(const bf16x8*)&VtL[(df * 16 + l16) * 138 + s * 32 + quad * 8];
                    O[0][df] = __builtin_amdgcn_mfma_f32_16x16x32_bf16(ap0, bv, O[0][df], 0, 0, 0);
                    O[1][df] = __builtin_amdgcn_mfma_f32_16x16x32_bf16(ap1, bv, O[1][df], 0, 0, 0);
                }
            }
        }

        // ---- epilogue ----
        #pragma unroll
        for (int qf = 0; qf < 2; ++qf)
            #pragma unroll
            for (int r = 0; r < 4; ++r) {
                float inv = 1.0f / l_i[qf][r];
                size_t srow = (size_t)b * S_LEN + q0 + wave * 32 + qf * 16 + quad * 4 + r;
                bf16* dst = Ctx + srow * D_MODEL + h * HDIM;
                #pragma unroll
                for (int df = 0; df < 4; ++df)
                    dst[df * 16 + l16] = (bf16)(O[qf][df][r] * inv);
            }
    }
}

extern "C" void kernel_launch(void* const* d_in, const int* in_sizes, int n_in,
                              void* d_out, int out_size, void* d_ws, size_t ws_size,
                              hipStream_t stream) {
    const float* x  = (const float*)d_in[0];
    const float* Wq = (const float*)d_in[1];
    const float* Wk = (const float*)d_in[2];
    const float* Wv = (const float*)d_in[3];
    const float* Wo = (const float*)d_in[4];

    char* p = (char*)d_ws;
    bf16* X16 = (bf16*)p; p += (size_t)4096 * 2048 * 2;
    bf16* WqT = (bf16*)p; p += (size_t)2048 * 2048 * 2;
    bf16* WkT = (bf16*)p; p += (size_t)512 * 2048 * 2;
    bf16* WvT = (bf16*)p; p += (size_t)512 * 2048 * 2;
    bf16* WoT = (bf16*)p; p += (size_t)2048 * 2048 * 2;
    bf16* Qf  = (bf16*)p; p += (size_t)4096 * 2048 * 2;
    bf16* Kf  = (bf16*)p; p += (size_t)4096 * 512 * 2;
    bf16* Vf  = (bf16*)p; p += (size_t)4096 * 512 * 2;
    bf16* Qr  = (bf16*)p; p += (size_t)4096 * 2048 * 2;
    bf16* Kr  = (bf16*)p; p += (size_t)4096 * 512 * 2;
    bf16* Vt  = (bf16*)p; p += (size_t)16 * 64 * 2048 * 2;
    bf16* Ctx = Qf;  // Qf dead after rope_relayout; reuse for attention output

    cvt_f32_bf16<<<8192, 256, 0, stream>>>(x, X16, 2097152);
    transpose_w<<<dim3(64, 64), dim3(32, 8), 0, stream>>>(Wq, WqT, 2048, 2048);
    transpose_w<<<dim3(16, 64), dim3(32, 8), 0, stream>>>(Wk, WkT, 2048, 512);
    transpose_w<<<dim3(16, 64), dim3(32, 8), 0, stream>>>(Wv, WvT, 2048, 512);
    transpose_w<<<dim3(64, 64), dim3(32, 8), 0, stream>>>(Wo, WoT, 2048, 2048);

    gemm_bt<true><<<dim3(16, 32), 256, 0, stream>>>(X16, WqT, (void*)Qf, 4096, 2048, 2048);
    gemm_bt<true><<<dim3(4, 32),  256, 0, stream>>>(X16, WkT, (void*)Kf, 4096, 512, 2048);
    gemm_bt<true><<<dim3(4, 32),  256, 0, stream>>>(X16, WvT, (void*)Vf, 4096, 512, 2048);

    rope_relayout<<<20480, 256, 0, stream>>>(Qf, Kf, Qr, Kr);
    transpose_v<<<dim3(64, 2, 16), dim3(32, 8), 0, stream>>>(Vf, Vt);
    attn_kernel<<<512, 256, 0, stream>>>(Qr, Kr, Vt, Ctx);

    gemm_bt<false><<<dim3(16, 32), 256, 0, stream>>>(Ctx, WoT, d_out, 4096, 2048, 2048);
}

// Round 3
// 379.837 us; speedup vs baseline: 1.7165x; 1.2050x over previous
//
#include <hip/hip_runtime.h>

typedef __bf16 bf16;
typedef __attribute__((ext_vector_type(8))) __bf16 bf16x8;
typedef __attribute__((ext_vector_type(4))) float f32x4;

#define S_LEN 2048
#define D_MODEL 2048
#define NHEADS 32
#define NKVH 8
#define HDIM 64
#define BATCH 2

__device__ __forceinline__ void async_cp16(const bf16* g, bf16* l) {
    __builtin_amdgcn_global_load_lds(
        (const __attribute__((address_space(1))) unsigned int*)g,
        (__attribute__((address_space(3))) unsigned int*)l, 16, 0, 0);
}

// ---------------- elementwise fp32 -> bf16 ----------------
__global__ void cvt_f32_bf16(const float* __restrict__ in, bf16* __restrict__ out, int n4) {
    int i = blockIdx.x * blockDim.x + threadIdx.x;
    if (i < n4) {
        float4 f = ((const float4*)in)[i];
        union { bf16 h[4]; uint2 u; } t;
        t.h[0] = (bf16)f.x; t.h[1] = (bf16)f.y; t.h[2] = (bf16)f.z; t.h[3] = (bf16)f.w;
        ((uint2*)out)[i] = t.u;
    }
}

// ---------------- W [K][N] fp32 -> Wt [N][K] bf16 ----------------
__global__ void transpose_w(const float* __restrict__ W, bf16* __restrict__ Wt, int K, int N) {
    __shared__ float tile[32][33];
    int kt = blockIdx.y * 32, nt = blockIdx.x * 32;
    int tx = threadIdx.x, ty = threadIdx.y;
    #pragma unroll
    for (int i = 0; i < 32; i += 8)
        tile[ty + i][tx] = W[(size_t)(kt + ty + i) * N + nt + tx];
    __syncthreads();
    #pragma unroll
    for (int i = 0; i < 32; i += 8)
        Wt[(size_t)(nt + ty + i) * K + kt + tx] = (bf16)tile[tx][ty + i];
}

// ---------------- V slice of QKV -> Vt [b*8+kvh][d][s] bf16 ----------------
__global__ void transpose_v(const bf16* __restrict__ QKV, bf16* __restrict__ Vt) {
    __shared__ bf16 tl[32][33];
    int z = blockIdx.z;               // b*8+kvh
    int s0 = blockIdx.x * 32, d0 = blockIdx.y * 32;
    int bb = z >> 3, hh = z & 7;
    int tx = threadIdx.x, ty = threadIdx.y;
    #pragma unroll
    for (int i = 0; i < 32; i += 8)
        tl[ty + i][tx] = QKV[((size_t)(bb * S_LEN + s0 + ty + i)) * 3072 + 2560 + hh * 64 + d0 + tx];
    __syncthreads();
    #pragma unroll
    for (int i = 0; i < 32; i += 8)
        Vt[((size_t)z * 64 + d0 + ty + i) * S_LEN + s0 + tx] = tl[tx][ty + i];
}

// ---------------- GEMM (m97 structure): C[M][N] = A[M][K] * Bt[N][K]^T ----------------
// 128x128 tile, K-step 32, global_load_lds 16B staging, XOR chunk swizzle.
template <bool OUT_BF16>
__global__ __launch_bounds__(256) void gemm_bt(const bf16* __restrict__ A,
                                               const bf16* __restrict__ Bt,
                                               void* __restrict__ Cv,
                                               int M, int N, int K) {
    __shared__ __align__(16) bf16 As[128 * 32];   // unpadded: row = 64 B = 4 x 16B chunks
    __shared__ __align__(16) bf16 Bs[128 * 32];

    const int tid  = threadIdx.x;
    const int wave = tid >> 6;
    const int lane = tid & 63;
    const int l16  = lane & 15;
    const int quad = lane >> 4;
    const int wrow = (wave >> 1) * 64;
    const int wcol = (wave & 1) * 64;
    const int m0 = blockIdx.y * 128;
    const int n0 = blockIdx.x * 128;

    // staging: instr j of wave covers rows [(wave*2+j)*16, +16); lane -> (row, chunk)
    const int csw = (lane & 3) ^ ((lane >> 2) & 3) ^ ((lane >> 4) & 3);
    const int r0  = (wave * 2 + 0) * 16 + (lane >> 2);
    const int r1  = (wave * 2 + 1) * 16 + (lane >> 2);
    const bf16* gA0 = A  + (size_t)(m0 + r0) * K + csw * 8;
    const bf16* gA1 = A  + (size_t)(m0 + r1) * K + csw * 8;
    const bf16* gB0 = Bt + (size_t)(n0 + r0) * K + csw * 8;
    const bf16* gB1 = Bt + (size_t)(n0 + r1) * K + csw * 8;
    bf16* lA0 = &As[(wave * 2 + 0) * 512];
    bf16* lA1 = &As[(wave * 2 + 1) * 512];
    bf16* lB0 = &Bs[(wave * 2 + 0) * 512];
    bf16* lB1 = &Bs[(wave * 2 + 1) * 512];

    // fragment-read swizzle (matches staging: row%16 == l16)
    const int sw = (l16 & 3) ^ ((l16 >> 2) & 3);

    f32x4 acc[4][4];
    #pragma unroll
    for (int mi = 0; mi < 4; ++mi)
        #pragma unroll
        for (int ni = 0; ni < 4; ++ni)
            acc[mi][ni] = (f32x4){0.f, 0.f, 0.f, 0.f};

    for (int k0 = 0; k0 < K; k0 += 32) {
        __syncthreads();
        async_cp16(gA0, lA0); async_cp16(gA1, lA1);
        async_cp16(gB0, lB0); async_cp16(gB1, lB1);
        gA0 += 32; gA1 += 32; gB0 += 32; gB1 += 32;
        __syncthreads();

        bf16x8 af[4], bfr[4];
        #pragma unroll
        for (int mi = 0; mi < 4; ++mi)
            af[mi] = *(const bf16x8*)&As[(wrow + mi * 16 + l16) * 32 + ((quad ^ sw) * 8)];
        #pragma unroll
        for (int ni = 0; ni < 4; ++ni)
            bfr[ni] = *(const bf16x8*)&Bs[(wcol + ni * 16 + l16) * 32 + ((quad ^ sw) * 8)];
        #pragma unroll
        for (int mi = 0; mi < 4; ++mi)
            #pragma unroll
            for (int ni = 0; ni < 4; ++ni)
                acc[mi][ni] = __builtin_amdgcn_mfma_f32_16x16x32_bf16(af[mi], bfr[ni], acc[mi][ni], 0, 0, 0);
    }

    #pragma unroll
    for (int mi = 0; mi < 4; ++mi) {
        #pragma unroll
        for (int ni = 0; ni < 4; ++ni) {
            #pragma unroll
            for (int r = 0; r < 4; ++r) {
                size_t row = (size_t)(m0 + wrow + mi * 16 + quad * 4 + r);
                size_t col = (size_t)(n0 + wcol + ni * 16 + l16);
                if (OUT_BF16) ((bf16*)Cv)[row * N + col] = (bf16)acc[mi][ni][r];
                else          ((float*)Cv)[row * N + col] = acc[mi][ni][r];
            }
        }
    }
}

// ---------------- RoPE + relayout from fused QKV (Q scaled by 1/8) ----------------
__global__ void rope_relayout(const bf16* __restrict__ QKV,
                              bf16* __restrict__ Qr, bf16* __restrict__ Kr) {
    const int QN = BATCH * S_LEN * NHEADS * 32;  // 4194304
    const int KN = BATCH * S_LEN * NKVH * 32;    // 1048576
    const float LC = 0.28782313662425572f;       // ln(10000)/32
    int idx = blockIdx.x * 256 + threadIdx.x;
    if (idx < QN) {
        int j = idx & 31, hh = (idx >> 5) & 31, s = (idx >> 10) & 2047, bb = idx >> 21;
        size_t src = ((size_t)(bb * S_LEN + s)) * 3072 + hh * HDIM + j;
        float x1 = (float)QKV[src], x2 = (float)QKV[src + 32];
        float ang = (float)s * __expf(-(float)j * LC);
        float sn, cs; sincosf(ang, &sn, &cs);
        size_t dst = ((size_t)((bb * NHEADS + hh) * S_LEN + s)) * HDIM + j;
        Qr[dst]      = (bf16)((x1 * cs - x2 * sn) * 0.125f);
        Qr[dst + 32] = (bf16)((x2 * cs + x1 * sn) * 0.125f);
    } else if (idx < QN + KN) {
        int t = idx - QN;
        int j = t & 31, hh = (t >> 5) & 7, s = (t >> 8) & 2047, bb = t >> 19;
        size_t src = ((size_t)(bb * S_LEN + s)) * 3072 + 2048 + hh * HDIM + j;
        float x1 = (float)QKV[src], x2 = (float)QKV[src + 32];
        float ang = (float)s * __expf(-(float)j * LC);
        float sn, cs; sincosf(ang, &sn, &cs);
        size_t dst = ((size_t)((bb * NKVH + hh) * S_LEN + s)) * HDIM + j;
        Kr[dst]      = (bf16)(x1 * cs - x2 * sn);
        Kr[dst + 32] = (bf16)(x2 * cs + x1 * sn);
    }
}

// ---------------- Flash attention (causal GQA) ----------------
// grid = 1024 (one 128-row q-tile per block, longest tiles dispatched first).
// block = 256 (4 waves), KV-tile 128 keys, global_load_lds staging w/ XOR swizzle.
__global__ __launch_bounds__(256) void attn_kernel(const bf16* __restrict__ Q,
                                                   const bf16* __restrict__ K,
                                                   const bf16* __restrict__ Vt,
                                                   bf16* __restrict__ Ctx) {
    __shared__ __align__(16) bf16 KsL[128 * 64];   // [key][dim], 128 B rows, 8 chunks
    __shared__ __align__(16) bf16 VtL[64 * 128];   // [dim][key], 256 B rows, 16 chunks
    __shared__ __align__(16) bf16 Ps[4 * 32 * 40]; // per-wave P relayout

    const int bx = blockIdx.x;
    const int qt = 15 - (bx >> 6);      // longest-first (LPT)
    const int bh = bx & 63;
    const int b  = bh >> 5;
    const int h  = bh & 31;
    const int kvh = h >> 2;
    const int tid = threadIdx.x;
    const int wave = tid >> 6;
    const int lane = tid & 63;
    const int l16  = lane & 15;
    const int quad = lane >> 4;

    const bf16* Qb = Q  + ((size_t)(b * NHEADS + h)) * S_LEN * HDIM;
    const bf16* Kb = K  + ((size_t)(b * NKVH + kvh)) * S_LEN * HDIM;
    const bf16* Vb = Vt + ((size_t)(b * NKVH + kvh)) * HDIM * S_LEN;
    bf16* Psw = &Ps[wave * 32 * 40];

    const int q0 = qt * 128;

    bf16x8 aq[2][2];
    #pragma unroll
    for (int qf = 0; qf < 2; ++qf)
        #pragma unroll
        for (int ks = 0; ks < 2; ++ks)
            aq[qf][ks] = *(const bf16x8*)(Qb + (size_t)(q0 + wave * 32 + qf * 16 + l16) * HDIM + ks * 32 + quad * 8);

    f32x4 O[2][4];
    float m_i[2][4], l_i[2][4];
    #pragma unroll
    for (int qf = 0; qf < 2; ++qf) {
        #pragma unroll
        for (int r = 0; r < 4; ++r) { m_i[qf][r] = -1e30f; l_i[qf][r] = 0.f; }
        #pragma unroll
        for (int df = 0; df < 4; ++df) O[qf][df] = (f32x4){0.f,0.f,0.f,0.f};
    }

    // staging lane maps (constant per thread)
    const int krow = lane >> 3, kslot = lane & 7;
    const int kc   = kslot ^ (krow & 7);
    const int vslot = lane & 15, vsub = lane >> 4;

    #pragma unroll 1
    for (int kt = 0; kt <= qt; ++kt) {
        const int k0 = kt * 128;
        __syncthreads();
        #pragma unroll
        for (int j = 0; j < 4; ++j) {
            int rbase = (wave * 4 + j) * 8;                 // K rows
            async_cp16(Kb + (size_t)(k0 + rbase + krow) * HDIM + kc * 8, &KsL[rbase * 64]);
            int d0 = (wave * 4 + j) * 4;                    // V rows (dims)
            int vrow = d0 + vsub;
            int vc = vslot ^ (vrow & 15);
            async_cp16(Vb + (size_t)vrow * S_LEN + k0 + vc * 8, &VtL[d0 * 128]);
        }
        __syncthreads();

        // ---- S = Q K^T (32q x 128k per wave) ----
        f32x4 sc[2][8];
        #pragma unroll
        for (int qf = 0; qf < 2; ++qf)
            #pragma unroll
            for (int kf = 0; kf < 8; ++kf)
                sc[qf][kf] = (f32x4){0.f,0.f,0.f,0.f};
        #pragma unroll
        for (int kf = 0; kf < 8; ++kf) {
            #pragma unroll
            for (int ks = 0; ks < 2; ++ks) {
                bf16x8 bk = *(const bf16x8*)&KsL[(kf * 16 + l16) * 64 + (((ks * 4 + quad) ^ (l16 & 7)) * 8)];
                sc[0][kf] = __builtin_amdgcn_mfma_f32_16x16x32_bf16(aq[0][ks], bk, sc[0][kf], 0, 0, 0);
                sc[1][kf] = __builtin_amdgcn_mfma_f32_16x16x32_bf16(aq[1][ks], bk, sc[1][kf], 0, 0, 0);
            }
        }

        if (kt == qt) {  // diagonal: causal mask (Q pre-scaled by 1/8)
            #pragma unroll
            for (int qf = 0; qf < 2; ++qf)
                #pragma unroll
                for (int kf = 0; kf < 8; ++kf)
                    #pragma unroll
                    for (int r = 0; r < 4; ++r) {
                        int key = kf * 16 + l16;
                        int qi  = wave * 32 + qf * 16 + quad * 4 + r;
                        if (key > qi) sc[qf][kf][r] = -1e30f;
                    }
        }

        // ---- online softmax ----
        float mx[2][4];
        #pragma unroll
        for (int qf = 0; qf < 2; ++qf)
            #pragma unroll
            for (int r = 0; r < 4; ++r) {
                float v = sc[qf][0][r];
                #pragma unroll
                for (int kf = 1; kf < 8; ++kf) v = fmaxf(v, sc[qf][kf][r]);
                mx[qf][r] = v;
            }
        #pragma unroll
        for (int off = 1; off < 16; off <<= 1)
            #pragma unroll
            for (int qf = 0; qf < 2; ++qf)
                #pragma unroll
                for (int r = 0; r < 4; ++r)
                    mx[qf][r] = fmaxf(mx[qf][r], __shfl_xor(mx[qf][r], off));

        #pragma unroll
        for (int qf = 0; qf < 2; ++qf)
            #pragma unroll
            for (int r = 0; r < 4; ++r) {
                float mn = fmaxf(m_i[qf][r], mx[qf][r]);
                float alpha = __expf(m_i[qf][r] - mn);
                m_i[qf][r] = mn;
                l_i[qf][r] *= alpha;
                #pragma unroll
                for (int df = 0; df < 4; ++df) O[qf][df][r] *= alpha;
            }

        float rs[2][4];
        #pragma unroll
        for (int qf = 0; qf < 2; ++qf)
            #pragma unroll
            for (int r = 0; r < 4; ++r) {
                float s = 0.f;
                #pragma unroll
                for (int kf = 0; kf < 8; ++kf) {
                    float pe = __expf(sc[qf][kf][r] - m_i[qf][r]);
                    sc[qf][kf][r] = pe;
                    s += pe;
                }
                rs[qf][r] = s;
            }
        #pragma unroll
        for (int off = 1; off < 16; off <<= 1)
            #pragma unroll
            for (int qf = 0; qf < 2; ++qf)
                #pragma unroll
                for (int r = 0; r < 4; ++r)
                    rs[qf][r] += __shfl_xor(rs[qf][r], off);
        #pragma unroll
        for (int qf = 0; qf < 2; ++qf)
            #pragma unroll
            for (int r = 0; r < 4; ++r)
                l_i[qf][r] += rs[qf][r];

        // ---- O += P V : 4 k-steps of 32 keys ----
        #pragma unroll
        for (int s = 0; s < 4; ++s) {
            #pragma unroll
            for (int qf = 0; qf < 2; ++qf)
                #pragma unroll
                for (int f = 0; f < 2; ++f)
                    #pragma unroll
                    for (int r = 0; r < 4; ++r)
                        Psw[(qf * 16 + quad * 4 + r) * 40 + f * 16 + l16] = (bf16)sc[qf][2 * s + f][r];
            bf16x8 ap0 = *(const bf16x8*)&Psw[l16 * 40 + quad * 8];
            bf16x8 ap1 = *(const bf16x8*)&Psw[(16 + l16) * 40 + quad * 8];
            #pragma unroll
            for (int df = 0; df < 4; ++df) {
                bf16x8 bv = *(const bf16x8*)&VtL[(df * 16 + l16) * 128 + (((s * 4 + quad) ^ l16) * 8)];
                O[0][df] = __builtin_amdgcn_mfma_f32_16x16x32_bf16(ap0, bv, O[0][df], 0, 0, 0);
                O[1][df] = __builtin_amdgcn_mfma_f32_16x16x32_bf16(ap1, bv, O[1][df], 0, 0, 0);
            }
        }
    }

    // ---- epilogue ----
    #pragma unroll
    for (int qf = 0; qf < 2; ++qf)
        #pragma unroll
        for (int r = 0; r < 4; ++r) {
            float inv = 1.0f / l_i[qf][r];
            size_t srow = (size_t)b * S_LEN + q0 + wave * 32 + qf * 16 + quad * 4 + r;
            bf16* dst = Ctx + srow * D_MODEL + h * HDIM;
            #pragma unroll
            for (int df = 0; df < 4; ++df)
                dst[df * 16 + l16] = (bf16)(O[qf][df][r] * inv);
        }
}

extern "C" void kernel_launch(void* const* d_in, const int* in_sizes, int n_in,
                              void* d_out, int out_size, void* d_ws, size_t ws_size,
                              hipStream_t stream) {
    const float* x  = (const float*)d_in[0];
    const float* Wq = (const float*)d_in[1];
    const float* Wk = (const float*)d_in[2];
    const float* Wv = (const float*)d_in[3];
    const float* Wo = (const float*)d_in[4];

    char* p = (char*)d_ws;
    bf16* X16 = (bf16*)p; p += (size_t)4096 * 2048 * 2;
    bf16* WqT = (bf16*)p; p += (size_t)2048 * 2048 * 2;   // WqT/WkT/WvT contiguous: fused N=3072
    bf16* WkT = (bf16*)p; p += (size_t)512 * 2048 * 2;
    bf16* WvT = (bf16*)p; p += (size_t)512 * 2048 * 2;
    bf16* WoT = (bf16*)p; p += (size_t)2048 * 2048 * 2;
    bf16* QKV = (bf16*)p; p += (size_t)4096 * 3072 * 2;
    bf16* Qr  = (bf16*)p; p += (size_t)4096 * 2048 * 2;
    bf16* Kr  = (bf16*)p; p += (size_t)4096 * 512 * 2;
    bf16* Vt  = (bf16*)p; p += (size_t)16 * 64 * 2048 * 2;
    bf16* Ctx = QKV;  // QKV dead after rope_relayout + transpose_v

    cvt_f32_bf16<<<8192, 256, 0, stream>>>(x, X16, 2097152);
    transpose_w<<<dim3(64, 64), dim3(32, 8), 0, stream>>>(Wq, WqT, 2048, 2048);
    transpose_w<<<dim3(16, 64), dim3(32, 8), 0, stream>>>(Wk, WkT, 2048, 512);
    transpose_w<<<dim3(16, 64), dim3(32, 8), 0, stream>>>(Wv, WvT, 2048, 512);
    transpose_w<<<dim3(64, 64), dim3(32, 8), 0, stream>>>(Wo, WoT, 2048, 2048);

    // fused QKV projection: [4096][2048] x [3072][2048]^T -> [4096][3072]
    gemm_bt<true><<<dim3(24, 32), 256, 0, stream>>>(X16, WqT, (void*)QKV, 4096, 3072, 2048);

    rope_relayout<<<20480, 256, 0, stream>>>(QKV, Qr, Kr);
    transpose_v<<<dim3(64, 2, 16), dim3(32, 8), 0, stream>>>(QKV, Vt);
    attn_kernel<<<1024, 256, 0, stream>>>(Qr, Kr, Vt, Ctx);

    gemm_bt<false><<<dim3(16, 32), 256, 0, stream>>>(Ctx, WoT, d_out, 4096, 2048, 2048);
}